// Round 1
// baseline (1785.318 us; speedup 1.0000x reference)
//
#include <hip/hip_runtime.h>
#include <hip/hip_bf16.h>
#include <math.h>

#define NN 8
#define CH 128
#define HH 36
#define WWI 36
#define PP 1296      // 36*36
#define OHD 34
#define OWD 34
#define DD 1156      // 34*34

// ---------------------------------------------------------------------------
// hconst[co] = b_h[co] + sum_ci w_h[co, 256+ci] * vc[ci]
// vc[c] = sum_ci c0[ci] * sum_k w_vc[c,ci,k]
// ---------------------------------------------------------------------------
__global__ void k_const(const float* __restrict__ c0, const float* __restrict__ w_vc,
                        const float* __restrict__ w_h, const float* __restrict__ b_h,
                        float* __restrict__ hconst)
{
    __shared__ float vc[CH];
    int c = threadIdx.x;
    float s = 0.f;
    for (int ci = 0; ci < CH; ++ci) {
        const float* wp = w_vc + ((size_t)c * CH + ci) * 9;
        float ws = 0.f;
#pragma unroll
        for (int k = 0; k < 9; ++k) ws += wp[k];
        s += c0[ci] * ws;
    }
    vc[c] = s;
    __syncthreads();
    float hs = b_h[c];
    for (int ci = 0; ci < CH; ++ci) hs += w_h[(size_t)c * (3 * CH) + 2 * CH + ci] * vc[ci];
    hconst[c] = hs;
}

// ---------------------------------------------------------------------------
// 1x1 conv: out[n,co,p] = act(bias[co] + sum_{ci<K0} W[co,ci]*in0[n,ci,p]
//                                      + sum_{ci}    W[co,K0+ci]*in1[n,ci,p])
// Tile 64co x 64p, K chunks of 32. Cout = 128 always.
// ---------------------------------------------------------------------------
__global__ __launch_bounds__(256)
void k_conv1x1(const float* __restrict__ in0, const float* __restrict__ in1,
               const float* __restrict__ W, const float* __restrict__ bias,
               float* __restrict__ out, int K0, int Ktot, int ldw, int act)
{
    __shared__ float s_in[32][64];
    __shared__ float s_w[32][68];
    const int t = threadIdx.x;
    const int tx = t & 15, ty = t >> 4;
    const int pbase = blockIdx.x * 64;
    const int cobase = blockIdx.y * 64;
    const int n = blockIdx.z;
    const int K1 = Ktot - K0;
    float acc[4][4] = {};

    for (int kb = 0; kb < Ktot; kb += 32) {
#pragma unroll
        for (int r = 0; r < 8; ++r) {
            int lin = t + r * 256;
            int ci = lin >> 6, pl = lin & 63;
            int kg = kb + ci;
            int p = pbase + pl;
            const float* src = (kg < K0) ? (in0 + (size_t)(n * K0 + kg) * PP)
                                         : (in1 + (size_t)(n * K1 + (kg - K0)) * PP);
            s_in[ci][pl] = (p < PP) ? src[p] : 0.f;
        }
#pragma unroll
        for (int r = 0; r < 8; ++r) {
            int lin = t + r * 256;
            int col = lin >> 5;     // co_l 0..63
            int cil = lin & 31;
            s_w[cil][col] = W[(size_t)(cobase + col) * ldw + kb + cil];
        }
        __syncthreads();
#pragma unroll
        for (int kk = 0; kk < 32; ++kk) {
            float4 i4 = *(const float4*)&s_in[kk][tx * 4];
            float4 w4 = *(const float4*)&s_w[kk][ty * 4];
            float iv[4] = {i4.x, i4.y, i4.z, i4.w};
            float wv[4] = {w4.x, w4.y, w4.z, w4.w};
#pragma unroll
            for (int v = 0; v < 4; ++v)
#pragma unroll
                for (int u = 0; u < 4; ++u) acc[v][u] += wv[v] * iv[u];
        }
        __syncthreads();
    }

    int p0 = pbase + tx * 4;
    if (p0 < PP) {   // PP % 4 == 0 so full float4 in-bounds
#pragma unroll
        for (int v = 0; v < 4; ++v) {
            int co = cobase + ty * 4 + v;
            float b = bias[co];
            float4 o;
            o.x = acc[v][0] + b; o.y = acc[v][1] + b;
            o.z = acc[v][2] + b; o.w = acc[v][3] + b;
            if (act) { o.x = tanhf(o.x); o.y = tanhf(o.y); o.z = tanhf(o.z); o.w = tanhf(o.w); }
            *(float4*)&out[((size_t)(n * CH + co)) * PP + p0] = o;
        }
    }
}

// ---------------------------------------------------------------------------
// 3x3 conv, thread computes 1 co x 4 consecutive cols. co is block-uniform
// so weight loads are scalar. SAMEPAD=1 -> SAME (36x36 out), 0 -> VALID (34x34).
// NSETS=2 computes two convs (k and v) sharing the staged input registers.
// ---------------------------------------------------------------------------
template <int SAMEPAD, int NSETS>
__global__ __launch_bounds__(64)
void k_conv3x3(const float* __restrict__ in, const float* __restrict__ w0,
               const float* __restrict__ w1, float* __restrict__ out0,
               float* __restrict__ out1, int oh, int ow)
{
    const int co = blockIdx.y;
    const int n = blockIdx.z;
    const int ngrp = (ow + 3) >> 2;      // 9
    int s = blockIdx.x * 64 + threadIdx.x;
    int orow = s / ngrp;
    int og = s - orow * ngrp;
    bool valid = (orow < oh);
    int oc0 = og * 4;

    const float* ip = in + (size_t)n * CH * PP;
    const float* wp0 = w0 + (size_t)co * CH * 9;
    const float* wp1 = w1 + (size_t)co * CH * 9;

    float acc0[4] = {0.f, 0.f, 0.f, 0.f};
    float acc1[4] = {0.f, 0.f, 0.f, 0.f};

    for (int ci = 0; ci < CH; ++ci) {
        const float* irow = ip + (size_t)ci * PP;
        float a[3][6];
#pragma unroll
        for (int ky = 0; ky < 3; ++ky) {
            int yy = orow + ky - SAMEPAD;
            bool yok = valid && (yy >= 0) && (yy < HH);
#pragma unroll
            for (int j = 0; j < 6; ++j) {
                int xx = oc0 + j - SAMEPAD;
                a[ky][j] = (yok && xx >= 0 && xx < WWI) ? irow[yy * WWI + xx] : 0.f;
            }
        }
#pragma unroll
        for (int ky = 0; ky < 3; ++ky)
#pragma unroll
            for (int kx = 0; kx < 3; ++kx) {
                float wv0 = wp0[ci * 9 + ky * 3 + kx];
                float wv1 = (NSETS > 1) ? wp1[ci * 9 + ky * 3 + kx] : 0.f;
#pragma unroll
                for (int u = 0; u < 4; ++u) {
                    float iv = a[ky][kx + u];
                    acc0[u] += wv0 * iv;
                    if (NSETS > 1) acc1[u] += wv1 * iv;
                }
            }
    }

    if (valid) {
        size_t ob = ((size_t)(n * CH + co)) * ((size_t)oh * ow) + (size_t)orow * ow;
#pragma unroll
        for (int u = 0; u < 4; ++u) {
            int oc = oc0 + u;
            if (oc < ow) {
                out0[ob + oc] = acc0[u];
                if (NSETS > 1) out1[ob + oc] = acc1[u];
            }
        }
    }
}

// ---------------------------------------------------------------------------
// scores[n,q,d] = sum_c qx[n,c,q] * kx[n,c,d]. Tile 64q x 64d, K=128 chunks 32.
// ---------------------------------------------------------------------------
__global__ __launch_bounds__(256)
void k_scores(const float* __restrict__ q, const float* __restrict__ k,
              float* __restrict__ sc)
{
    __shared__ float s_q[32][64];
    __shared__ float s_k[32][64];
    const int t = threadIdx.x;
    const int tx = t & 15, ty = t >> 4;
    const int dbase = blockIdx.x * 64;
    const int qbase = blockIdx.y * 64;
    const int n = blockIdx.z;
    const float* qp = q + (size_t)n * CH * PP;
    const float* kp = k + (size_t)n * CH * DD;
    float acc[4][4] = {};

    for (int kb = 0; kb < CH; kb += 32) {
#pragma unroll
        for (int r = 0; r < 8; ++r) {
            int lin = t + r * 256;
            int ci = lin >> 6, l = lin & 63;
            int qq = qbase + l;
            s_q[ci][l] = (qq < PP) ? qp[(size_t)(kb + ci) * PP + qq] : 0.f;
        }
#pragma unroll
        for (int r = 0; r < 8; ++r) {
            int lin = t + r * 256;
            int ci = lin >> 6, l = lin & 63;
            int dd = dbase + l;
            s_k[ci][l] = (dd < DD) ? kp[(size_t)(kb + ci) * DD + dd] : 0.f;
        }
        __syncthreads();
#pragma unroll
        for (int kk = 0; kk < 32; ++kk) {
            float4 d4 = *(const float4*)&s_k[kk][tx * 4];
            float4 q4 = *(const float4*)&s_q[kk][ty * 4];
            float dv[4] = {d4.x, d4.y, d4.z, d4.w};
            float qv[4] = {q4.x, q4.y, q4.z, q4.w};
#pragma unroll
            for (int v = 0; v < 4; ++v)
#pragma unroll
                for (int u = 0; u < 4; ++u) acc[v][u] += qv[v] * dv[u];
        }
        __syncthreads();
    }

    int d0 = dbase + tx * 4;
    if (d0 < DD) {   // DD % 4 == 0
#pragma unroll
        for (int v = 0; v < 4; ++v) {
            int qq = qbase + ty * 4 + v;
            if (qq < PP) {
                float4 o = {acc[v][0], acc[v][1], acc[v][2], acc[v][3]};
                *(float4*)&sc[((size_t)n * PP + qq) * DD + d0] = o;
            }
        }
    }
}

// ---------------------------------------------------------------------------
// row softmax over D=1156, one block per (n,q) row
// ---------------------------------------------------------------------------
__global__ __launch_bounds__(256)
void k_softmax(float* __restrict__ sc)
{
    const int row = blockIdx.x;
    float* p = sc + (size_t)row * DD;
    const int t = threadIdx.x;
    __shared__ float sm[4];
    float vals[5];
    float m = -1e30f;
#pragma unroll
    for (int r = 0; r < 5; ++r) {
        int i = t + r * 256;
        float v = (i < DD) ? p[i] : -1e30f;
        vals[r] = v;
        m = fmaxf(m, v);
    }
#pragma unroll
    for (int off = 32; off > 0; off >>= 1) m = fmaxf(m, __shfl_xor(m, off, 64));
    int lane = t & 63, wid = t >> 6;
    if (lane == 0) sm[wid] = m;
    __syncthreads();
    m = fmaxf(fmaxf(sm[0], sm[1]), fmaxf(sm[2], sm[3]));
    float s = 0.f;
#pragma unroll
    for (int r = 0; r < 5; ++r) {
        int i = t + r * 256;
        if (i < DD) { float e = __expf(vals[r] - m); vals[r] = e; s += e; }
    }
#pragma unroll
    for (int off = 32; off > 0; off >>= 1) s += __shfl_xor(s, off, 64);
    __syncthreads();               // everyone done reading sm (max phase)
    if (lane == 0) sm[wid] = s;
    __syncthreads();
    float inv = 1.f / (sm[0] + sm[1] + sm[2] + sm[3]);
#pragma unroll
    for (int r = 0; r < 5; ++r) {
        int i = t + r * 256;
        if (i < DD) p[i] = vals[r] * inv;
    }
}

// ---------------------------------------------------------------------------
// a0[n,c,q] = sum_d vx[n,c,d] * attn[n,q,d]. Tile 64c x 64q, K=1156 chunks 32.
// ---------------------------------------------------------------------------
__global__ __launch_bounds__(256)
void k_av(const float* __restrict__ vx, const float* __restrict__ at,
          float* __restrict__ a0)
{
    __shared__ float s_v[32][68];
    __shared__ float s_a[32][68];
    const int t = threadIdx.x;
    const int tx = t & 15, ty = t >> 4;
    const int qbase = blockIdx.x * 64;
    const int cbase = blockIdx.y * 64;
    const int n = blockIdx.z;
    const float* vp = vx + (size_t)n * CH * DD;
    const float* ap = at + (size_t)n * PP * DD;
    float acc[4][4] = {};

    for (int db = 0; db < DD; db += 32) {
#pragma unroll
        for (int r = 0; r < 8; ++r) {
            int lin = t + r * 256;
            int cl = lin >> 5, dl = lin & 31;
            int dg = db + dl;
            s_v[dl][cl] = (dg < DD) ? vp[(size_t)(cbase + cl) * DD + dg] : 0.f;
        }
#pragma unroll
        for (int r = 0; r < 8; ++r) {
            int lin = t + r * 256;
            int ql = lin >> 5, dl = lin & 31;
            int dg = db + dl;
            int qq = qbase + ql;
            s_a[dl][ql] = (dg < DD && qq < PP) ? ap[(size_t)qq * DD + dg] : 0.f;
        }
        __syncthreads();
#pragma unroll
        for (int kk = 0; kk < 32; ++kk) {
            float4 q4 = *(const float4*)&s_a[kk][tx * 4];
            float4 c4 = *(const float4*)&s_v[kk][ty * 4];
            float qv[4] = {q4.x, q4.y, q4.z, q4.w};
            float cv[4] = {c4.x, c4.y, c4.z, c4.w};
#pragma unroll
            for (int v = 0; v < 4; ++v)
#pragma unroll
                for (int u = 0; u < 4; ++u) acc[v][u] += cv[v] * qv[u];
        }
        __syncthreads();
    }

    int q0 = qbase + tx * 4;
    if (q0 < PP) {
#pragma unroll
        for (int v = 0; v < 4; ++v) {
            int cc = cbase + ty * 4 + v;
            float4 o = {acc[v][0], acc[v][1], acc[v][2], acc[v][3]};
            *(float4*)&a0[((size_t)(n * CH + cc)) * PP + q0] = o;
        }
    }
}

// ---------------------------------------------------------------------------
extern "C" void kernel_launch(void* const* d_in, const int* in_sizes, int n_in,
                              void* d_out, int out_size, void* d_ws, size_t ws_size,
                              hipStream_t stream)
{
    const float* inp  = (const float*)d_in[0];
    const float* c0   = (const float*)d_in[1];
    const float* w_x  = (const float*)d_in[2];
    const float* b_x  = (const float*)d_in[3];
    const float* w_qx = (const float*)d_in[4];
    const float* w_kx = (const float*)d_in[6];
    const float* w_vx = (const float*)d_in[8];
    const float* w_vc = (const float*)d_in[9];
    const float* w_h  = (const float*)d_in[14];
    const float* b_h  = (const float*)d_in[15];
    const float* w_o  = (const float*)d_in[16];
    const float* b_o  = (const float*)d_in[17];
    float* out = (float*)d_out;

    float* ws = (float*)d_ws;
    float* x      = ws;                   // 8*128*1296 = 1327104
    float* qx     = x + 1327104;          // 1327104
    float* kx     = qx + 1327104;         // 8*128*1156 = 1183744
    float* vx     = kx + 1183744;         // 1183744
    float* a0     = vx + 1183744;         // 1327104
    float* hbuf   = a0 + 1327104;         // 1327104
    float* hconst = hbuf + 1327104;       // 128
    float* sc     = hconst + 128;         // 8*1296*1156 = 11985408

    hipLaunchKernelGGL(k_const, dim3(1), dim3(128), 0, stream, c0, w_vc, w_h, b_h, hconst);

    // x = proj_x(inp) + b_x
    hipLaunchKernelGGL(k_conv1x1, dim3(21, 2, NN), dim3(256), 0, stream,
                       inp, inp, w_x, b_x, x, 128, 128, 128, 0);

    // q = 3x3 SAME(x)
    hipLaunchKernelGGL((k_conv3x3<1, 1>), dim3(6, 128, NN), dim3(64), 0, stream,
                       x, w_qx, w_qx, qx, qx, 36, 36);
    // k, v = 3x3 VALID(x)
    hipLaunchKernelGGL((k_conv3x3<0, 2>), dim3(5, 128, NN), dim3(64), 0, stream,
                       x, w_kx, w_vx, kx, vx, 34, 34);

    // scores = q^T k ; softmax over d ; a0 = v attn^T
    hipLaunchKernelGGL(k_scores, dim3(19, 21, NN), dim3(256), 0, stream, qx, kx, sc);
    hipLaunchKernelGGL(k_softmax, dim3(NN * PP), dim3(256), 0, stream, sc);
    hipLaunchKernelGGL(k_av, dim3(21, 2, NN), dim3(256), 0, stream, vx, sc, a0);

    // h = tanh(w_h . [x ; a0] + hconst)   (hconst folds b_h + w_h[:,256:384].v_c)
    hipLaunchKernelGGL(k_conv1x1, dim3(21, 2, NN), dim3(256), 0, stream,
                       x, a0, w_h, hconst, hbuf, 128, 256, 384, 1);

    // out = w_o . h + b_o
    hipLaunchKernelGGL(k_conv1x1, dim3(21, 2, NN), dim3(256), 0, stream,
                       hbuf, hbuf, w_o, b_o, out, 128, 128, 128, 0);
}

// Round 2
// 503.156 us; speedup vs baseline: 3.5482x; 3.5482x over previous
//
#include <hip/hip_runtime.h>
#include <hip/hip_bf16.h>
#include <math.h>

#define NN 8
#define CH 128
#define HH 36
#define WWI 36
#define PP 1296      // 36*36
#define DD 1156      // 34*34
#define DP 1160      // v row padded so 16B vector loads stay aligned
#define KC 1152      // 128*9

typedef __attribute__((ext_vector_type(8))) short short8;
typedef __attribute__((ext_vector_type(4))) float f32x4;

__device__ inline unsigned short f2bf(float f) {
    __hip_bfloat16 h = __float2bfloat16(f);
    return __builtin_bit_cast(unsigned short, h);
}
__device__ inline unsigned int pack2(float a, float b) {
    return (unsigned int)f2bf(a) | ((unsigned int)f2bf(b) << 16);
}

// ---------------------------------------------------------------------------
// hconst[co] = b_h[co] + sum_ci w_h[co, 256+ci] * vc[ci]
// vc[c] = sum_ci c0[ci] * sum_k w_vc[c,ci,k]   (the b=1 attention branch folds
// to a constant because c is spatially uniform -> softmax is uniform)
// ---------------------------------------------------------------------------
__global__ void k_const(const float* __restrict__ c0, const float* __restrict__ w_vc,
                        const float* __restrict__ w_h, const float* __restrict__ b_h,
                        float* __restrict__ hconst)
{
    __shared__ float vc[CH];
    int c = threadIdx.x;
    float s = 0.f;
    for (int ci = 0; ci < CH; ++ci) {
        const float* wp = w_vc + ((size_t)c * CH + ci) * 9;
        float ws = 0.f;
#pragma unroll
        for (int k = 0; k < 9; ++k) ws += wp[k];
        s += c0[ci] * ws;
    }
    vc[c] = s;
    __syncthreads();
    float hs = b_h[c];
    for (int ci = 0; ci < CH; ++ci) hs += w_h[(size_t)c * (3 * CH) + 2 * CH + ci] * vc[ci];
    hconst[c] = hs;
}

// cast 3x3 weights to bf16: wq -> wq_bf[128][1152]; wk,wv -> wkv_bf[256][1152]
__global__ void k_cast_w(const float* __restrict__ wq, const float* __restrict__ wk,
                         const float* __restrict__ wv, unsigned short* __restrict__ wq_bf,
                         unsigned short* __restrict__ wkv_bf)
{
    int idx = blockIdx.x * 256 + threadIdx.x;   // 147456 = 128*1152
    wq_bf[idx] = f2bf(wq[idx]);
    wkv_bf[idx] = f2bf(wk[idx]);
    wkv_bf[147456 + idx] = f2bf(wv[idx]);
}

// ---------------------------------------------------------------------------
// fp32 1x1 conv (proj / h / out). Optionally mirrors output to bf16.
// ---------------------------------------------------------------------------
__global__ __launch_bounds__(256)
void k_conv1x1(const float* __restrict__ in0, const float* __restrict__ in1,
               const float* __restrict__ W, const float* __restrict__ bias,
               float* __restrict__ out, unsigned short* __restrict__ outb,
               int K0, int Ktot, int ldw, int act)
{
    __shared__ float s_in[32][64];
    __shared__ float s_w[32][68];
    const int t = threadIdx.x;
    const int tx = t & 15, ty = t >> 4;
    const int pbase = blockIdx.x * 64;
    const int cobase = blockIdx.y * 64;
    const int n = blockIdx.z;
    const int K1 = Ktot - K0;
    float acc[4][4] = {};

    for (int kb = 0; kb < Ktot; kb += 32) {
#pragma unroll
        for (int r = 0; r < 8; ++r) {
            int lin = t + r * 256;
            int ci = lin >> 6, pl = lin & 63;
            int kg = kb + ci;
            int p = pbase + pl;
            const float* src = (kg < K0) ? (in0 + (size_t)(n * K0 + kg) * PP)
                                         : (in1 + (size_t)(n * K1 + (kg - K0)) * PP);
            s_in[ci][pl] = (p < PP) ? src[p] : 0.f;
        }
#pragma unroll
        for (int r = 0; r < 8; ++r) {
            int lin = t + r * 256;
            int col = lin >> 5;
            int cil = lin & 31;
            s_w[cil][col] = W[(size_t)(cobase + col) * ldw + kb + cil];
        }
        __syncthreads();
#pragma unroll
        for (int kk = 0; kk < 32; ++kk) {
            float4 i4 = *(const float4*)&s_in[kk][tx * 4];
            float4 w4 = *(const float4*)&s_w[kk][ty * 4];
            float iv[4] = {i4.x, i4.y, i4.z, i4.w};
            float wv[4] = {w4.x, w4.y, w4.z, w4.w};
#pragma unroll
            for (int v = 0; v < 4; ++v)
#pragma unroll
                for (int u = 0; u < 4; ++u) acc[v][u] += wv[v] * iv[u];
        }
        __syncthreads();
    }

    int p0 = pbase + tx * 4;
    if (p0 < PP) {
#pragma unroll
        for (int v = 0; v < 4; ++v) {
            int co = cobase + ty * 4 + v;
            float b = bias[co];
            float4 o;
            o.x = acc[v][0] + b; o.y = acc[v][1] + b;
            o.z = acc[v][2] + b; o.w = acc[v][3] + b;
            if (act) { o.x = tanhf(o.x); o.y = tanhf(o.y); o.z = tanhf(o.z); o.w = tanhf(o.w); }
            size_t ob = ((size_t)(n * CH + co)) * PP + p0;
            *(float4*)&out[ob] = o;
            if (outb) {
                uint2 u;
                u.x = pack2(o.x, o.y); u.y = pack2(o.z, o.w);
                *(uint2*)&outb[ob] = u;
            }
        }
    }
}

// ---------------------------------------------------------------------------
// q conv (3x3 SAME) as implicit-GEMM MFMA: M=128 co, N=64 p tile, K=1152.
// Output transposed bf16 q_t[n][p][co] (A-operand layout for scores).
// ---------------------------------------------------------------------------
__global__ __launch_bounds__(256)
void k_conv_q(const unsigned short* __restrict__ xb, const unsigned short* __restrict__ wb,
              unsigned short* __restrict__ qt)
{
    __shared__ unsigned short lds_a[CH * 40];
    __shared__ unsigned short lds_b[64 * 40];
    const int t = threadIdx.x;
    const int wave = t >> 6, lane = t & 63;
    const int quad = lane >> 4, lrow = lane & 15;
    const int pbase = blockIdx.x * 64;
    const int n = blockIdx.y;
    const unsigned short* xn = xb + (size_t)n * CH * PP;

    const int p = pbase + lane;
    const int pr = p / 36, pc = p - pr * 36;
    const bool pok = p < PP;
    const int mbase = wave * 32;
    f32x4 acc[2][4] = {};

    for (int kb = 0; kb < KC; kb += 32) {
#pragma unroll
        for (int r = 0; r < 2; ++r) {
            int row = r * 64 + (t >> 2);
            int kseg = (t & 3) * 8;
            *(uint4*)&lds_a[row * 40 + kseg] = *(const uint4*)&wb[(size_t)row * KC + kb + kseg];
        }
#pragma unroll
        for (int r = 0; r < 8; ++r) {
            int kl = r * 4 + wave;
            int k = kb + kl;
            int ci = k / 9;
            int rem = k - ci * 9;
            int ky = rem / 3, kx = rem - ky * 3;
            int yy = pr + ky - 1, xx = pc + kx - 1;
            unsigned short v = 0;
            if (pok && yy >= 0 && yy < HH && xx >= 0 && xx < WWI)
                v = xn[ci * PP + yy * WWI + xx];
            lds_b[lane * 40 + kl] = v;
        }
        __syncthreads();
        short8 afr[2], bfr[4];
#pragma unroll
        for (int mi = 0; mi < 2; ++mi)
            afr[mi] = *(const short8*)&lds_a[(mbase + mi * 16 + lrow) * 40 + quad * 8];
#pragma unroll
        for (int ni = 0; ni < 4; ++ni)
            bfr[ni] = *(const short8*)&lds_b[(ni * 16 + lrow) * 40 + quad * 8];
#pragma unroll
        for (int mi = 0; mi < 2; ++mi)
#pragma unroll
            for (int ni = 0; ni < 4; ++ni)
                acc[mi][ni] = __builtin_amdgcn_mfma_f32_16x16x32_bf16(afr[mi], bfr[ni], acc[mi][ni], 0, 0, 0);
        __syncthreads();
    }

    unsigned short* qn = qt + (size_t)n * PP * CH;
#pragma unroll
    for (int ni = 0; ni < 4; ++ni) {
        int np = pbase + ni * 16 + lrow;
        if (np < PP) {
#pragma unroll
            for (int mi = 0; mi < 2; ++mi) {
                int m = mbase + mi * 16 + quad * 4;
                uint2 u;
                u.x = pack2(acc[mi][ni][0], acc[mi][ni][1]);
                u.y = pack2(acc[mi][ni][2], acc[mi][ni][3]);
                *(uint2*)&qn[(size_t)np * CH + m] = u;
            }
        }
    }
}

// ---------------------------------------------------------------------------
// k+v conv (3x3 VALID) fused: M=256 (k rows 0..127, v rows 128..255), N=64 d,
// K=1152. k stored transposed bf16 k_t[n][d][co]; v natural bf16 v[n][c][DP].
// ---------------------------------------------------------------------------
__global__ __launch_bounds__(256)
void k_conv_kv(const unsigned short* __restrict__ xb, const unsigned short* __restrict__ wb,
               unsigned short* __restrict__ kt, unsigned short* __restrict__ vb)
{
    __shared__ unsigned short lds_a[256 * 40];
    __shared__ unsigned short lds_b[64 * 40];
    const int t = threadIdx.x;
    const int wave = t >> 6, lane = t & 63;
    const int quad = lane >> 4, lrow = lane & 15;
    const int dbase = blockIdx.x * 64;
    const int n = blockIdx.y;
    const unsigned short* xn = xb + (size_t)n * CH * PP;

    const int d = dbase + lane;
    const int pr = d / 34, pc = d - pr * 34;
    const bool dok = d < DD;
    const int mbase = wave * 64;
    f32x4 acc[4][4] = {};

    for (int kb = 0; kb < KC; kb += 32) {
#pragma unroll
        for (int r = 0; r < 4; ++r) {
            int row = r * 64 + (t >> 2);
            int kseg = (t & 3) * 8;
            *(uint4*)&lds_a[row * 40 + kseg] = *(const uint4*)&wb[(size_t)row * KC + kb + kseg];
        }
#pragma unroll
        for (int r = 0; r < 8; ++r) {
            int kl = r * 4 + wave;
            int k = kb + kl;
            int ci = k / 9;
            int rem = k - ci * 9;
            int ky = rem / 3, kx = rem - ky * 3;
            unsigned short v = 0;
            if (dok) v = xn[ci * PP + (pr + ky) * WWI + (pc + kx)];
            lds_b[lane * 40 + kl] = v;
        }
        __syncthreads();
        short8 afr[4], bfr[4];
#pragma unroll
        for (int mi = 0; mi < 4; ++mi)
            afr[mi] = *(const short8*)&lds_a[(mbase + mi * 16 + lrow) * 40 + quad * 8];
#pragma unroll
        for (int ni = 0; ni < 4; ++ni)
            bfr[ni] = *(const short8*)&lds_b[(ni * 16 + lrow) * 40 + quad * 8];
#pragma unroll
        for (int mi = 0; mi < 4; ++mi)
#pragma unroll
            for (int ni = 0; ni < 4; ++ni)
                acc[mi][ni] = __builtin_amdgcn_mfma_f32_16x16x32_bf16(afr[mi], bfr[ni], acc[mi][ni], 0, 0, 0);
        __syncthreads();
    }

    unsigned short* kn = kt + (size_t)n * DD * CH;
    unsigned short* vn = vb + (size_t)n * CH * DP;
#pragma unroll
    for (int ni = 0; ni < 4; ++ni) {
        int nd = dbase + ni * 16 + lrow;
        if (nd < DD) {
#pragma unroll
            for (int mi = 0; mi < 4; ++mi) {
                int m = mbase + mi * 16 + quad * 4;
                if (m < 128) {
                    uint2 u;
                    u.x = pack2(acc[mi][ni][0], acc[mi][ni][1]);
                    u.y = pack2(acc[mi][ni][2], acc[mi][ni][3]);
                    *(uint2*)&kn[(size_t)nd * CH + m] = u;
                } else {
#pragma unroll
                    for (int r = 0; r < 4; ++r)
                        vn[(size_t)(m - 128 + r) * DP + nd] = f2bf(acc[mi][ni][r]);
                }
            }
        }
    }
}

// ---------------------------------------------------------------------------
// scores[n,q,d] = sum_c q_t[q][c] * k_t[d][c].  M=128q x N=128d tile, K=128.
// ---------------------------------------------------------------------------
__global__ __launch_bounds__(256)
void k_scores(const unsigned short* __restrict__ qt, const unsigned short* __restrict__ kt,
              float* __restrict__ sc)
{
    __shared__ unsigned short lds_a[128 * 40];
    __shared__ unsigned short lds_b[128 * 40];
    const int t = threadIdx.x;
    const int wave = t >> 6, lane = t & 63;
    const int quad = lane >> 4, lrow = lane & 15;
    const int dbase = blockIdx.x * 128;
    const int qbase = blockIdx.y * 128;
    const int n = blockIdx.z;
    const unsigned short* qn = qt + (size_t)n * PP * CH;
    const unsigned short* kn = kt + (size_t)n * DD * CH;
    const int mbase = wave * 32;
    f32x4 acc[2][8] = {};

    for (int kb = 0; kb < CH; kb += 32) {
#pragma unroll
        for (int r = 0; r < 2; ++r) {
            int row = r * 64 + (t >> 2);
            int kseg = (t & 3) * 8;
            int q = qbase + row;
            uint4 val = make_uint4(0, 0, 0, 0);
            if (q < PP) val = *(const uint4*)&qn[(size_t)q * CH + kb + kseg];
            *(uint4*)&lds_a[row * 40 + kseg] = val;
        }
#pragma unroll
        for (int r = 0; r < 2; ++r) {
            int row = r * 64 + (t >> 2);
            int kseg = (t & 3) * 8;
            int dd = dbase + row;
            uint4 val = make_uint4(0, 0, 0, 0);
            if (dd < DD) val = *(const uint4*)&kn[(size_t)dd * CH + kb + kseg];
            *(uint4*)&lds_b[row * 40 + kseg] = val;
        }
        __syncthreads();
        short8 afr[2], bfr[8];
#pragma unroll
        for (int mi = 0; mi < 2; ++mi)
            afr[mi] = *(const short8*)&lds_a[(mbase + mi * 16 + lrow) * 40 + quad * 8];
#pragma unroll
        for (int ni = 0; ni < 8; ++ni)
            bfr[ni] = *(const short8*)&lds_b[(ni * 16 + lrow) * 40 + quad * 8];
#pragma unroll
        for (int mi = 0; mi < 2; ++mi)
#pragma unroll
            for (int ni = 0; ni < 8; ++ni)
                acc[mi][ni] = __builtin_amdgcn_mfma_f32_16x16x32_bf16(afr[mi], bfr[ni], acc[mi][ni], 0, 0, 0);
        __syncthreads();
    }

#pragma unroll
    for (int mi = 0; mi < 2; ++mi)
#pragma unroll
        for (int r = 0; r < 4; ++r) {
            int q = qbase + mbase + mi * 16 + quad * 4 + r;
            if (q < PP) {
#pragma unroll
                for (int ni = 0; ni < 8; ++ni) {
                    int dd = dbase + ni * 16 + lrow;
                    if (dd < DD) sc[((size_t)n * PP + q) * DD + dd] = acc[mi][ni][r];
                }
            }
        }
}

// ---------------------------------------------------------------------------
// row softmax over D=1156 (fp32 in), bf16 out
// ---------------------------------------------------------------------------
__global__ __launch_bounds__(256)
void k_softmax(const float* __restrict__ sc, unsigned short* __restrict__ at)
{
    const int row = blockIdx.x;
    const float* p = sc + (size_t)row * DD;
    unsigned short* o = at + (size_t)row * DD;
    const int t = threadIdx.x;
    __shared__ float sm[4];
    float vals[5];
    float m = -1e30f;
#pragma unroll
    for (int r = 0; r < 5; ++r) {
        int i = t + r * 256;
        float v = (i < DD) ? p[i] : -1e30f;
        vals[r] = v;
        m = fmaxf(m, v);
    }
#pragma unroll
    for (int off = 32; off > 0; off >>= 1) m = fmaxf(m, __shfl_xor(m, off, 64));
    int lane = t & 63, wid = t >> 6;
    if (lane == 0) sm[wid] = m;
    __syncthreads();
    m = fmaxf(fmaxf(sm[0], sm[1]), fmaxf(sm[2], sm[3]));
    float s = 0.f;
#pragma unroll
    for (int r = 0; r < 5; ++r) {
        int i = t + r * 256;
        if (i < DD) { float e = __expf(vals[r] - m); vals[r] = e; s += e; }
    }
#pragma unroll
    for (int off = 32; off > 0; off >>= 1) s += __shfl_xor(s, off, 64);
    __syncthreads();
    if (lane == 0) sm[wid] = s;
    __syncthreads();
    float inv = 1.f / (sm[0] + sm[1] + sm[2] + sm[3]);
#pragma unroll
    for (int r = 0; r < 5; ++r) {
        int i = t + r * 256;
        if (i < DD) o[i] = f2bf(vals[r] * inv);
    }
}

// ---------------------------------------------------------------------------
// a0[n,c,q] = sum_d v[c][d] * attn[q][d].  M=128c x N=64q tile, K=1156.
// ---------------------------------------------------------------------------
__global__ __launch_bounds__(256)
void k_av(const unsigned short* __restrict__ vb, const unsigned short* __restrict__ at,
          float* __restrict__ a0)
{
    __shared__ unsigned short lds_a[128 * 40];
    __shared__ unsigned short lds_b[64 * 40];
    const int t = threadIdx.x;
    const int wave = t >> 6, lane = t & 63;
    const int quad = lane >> 4, lrow = lane & 15;
    const int qbase = blockIdx.x * 64;
    const int n = blockIdx.y;
    const unsigned short* vn = vb + (size_t)n * CH * DP;
    const unsigned short* an = at + (size_t)n * PP * DD;
    const int mbase = wave * 32;
    f32x4 acc[2][4] = {};

    for (int db = 0; db < 1184; db += 32) {
        bool full = (db + 32 <= DD);
#pragma unroll
        for (int r = 0; r < 2; ++r) {
            int row = r * 64 + (t >> 2);
            int dseg = (t & 3) * 8;
            if (full) {
                *(uint4*)&lds_a[row * 40 + dseg] = *(const uint4*)&vn[(size_t)row * DP + db + dseg];
            } else {
#pragma unroll
                for (int j = 0; j < 8; ++j) {
                    int dg = db + dseg + j;
                    lds_a[row * 40 + dseg + j] = (dg < DD) ? vn[(size_t)row * DP + dg] : 0;
                }
            }
        }
#pragma unroll
        for (int r = 0; r < 8; ++r) {
            int ql = r * 8 + (t >> 5);
            int dl = t & 31;
            int q = qbase + ql;
            int dg = db + dl;
            unsigned short val = 0;
            if (q < PP && dg < DD) val = an[(size_t)q * DD + dg];
            lds_b[ql * 40 + dl] = val;
        }
        __syncthreads();
        short8 afr[2], bfr[4];
#pragma unroll
        for (int mi = 0; mi < 2; ++mi)
            afr[mi] = *(const short8*)&lds_a[(mbase + mi * 16 + lrow) * 40 + quad * 8];
#pragma unroll
        for (int ni = 0; ni < 4; ++ni)
            bfr[ni] = *(const short8*)&lds_b[(ni * 16 + lrow) * 40 + quad * 8];
#pragma unroll
        for (int mi = 0; mi < 2; ++mi)
#pragma unroll
            for (int ni = 0; ni < 4; ++ni)
                acc[mi][ni] = __builtin_amdgcn_mfma_f32_16x16x32_bf16(afr[mi], bfr[ni], acc[mi][ni], 0, 0, 0);
        __syncthreads();
    }

    float* a0n = a0 + (size_t)n * CH * PP;
#pragma unroll
    for (int mi = 0; mi < 2; ++mi)
#pragma unroll
        for (int ni = 0; ni < 4; ++ni) {
            int q = qbase + ni * 16 + lrow;
            if (q < PP) {
#pragma unroll
                for (int r = 0; r < 4; ++r) {
                    int c = mbase + mi * 16 + quad * 4 + r;
                    a0n[(size_t)c * PP + q] = acc[mi][ni][r];
                }
            }
        }
}

// ---------------------------------------------------------------------------
extern "C" void kernel_launch(void* const* d_in, const int* in_sizes, int n_in,
                              void* d_out, int out_size, void* d_ws, size_t ws_size,
                              hipStream_t stream)
{
    const float* inp  = (const float*)d_in[0];
    const float* c0   = (const float*)d_in[1];
    const float* w_x  = (const float*)d_in[2];
    const float* b_x  = (const float*)d_in[3];
    const float* w_qx = (const float*)d_in[4];
    const float* w_kx = (const float*)d_in[6];
    const float* w_vx = (const float*)d_in[8];
    const float* w_vc = (const float*)d_in[9];
    const float* w_h  = (const float*)d_in[14];
    const float* b_h  = (const float*)d_in[15];
    const float* w_o  = (const float*)d_in[16];
    const float* b_o  = (const float*)d_in[17];
    float* out = (float*)d_out;

    char* w = (char*)d_ws;
    float* x            = (float*)(w);                      // 5,308,416 B
    float* a0           = (float*)(w + 5308416);            // 5,308,416 B
    float* sc           = (float*)(w + 10616832);           // 47,941,632 B
    unsigned short* attn = (unsigned short*)(w + 58558464); // 23,970,816 B
    unsigned short* x_bf = (unsigned short*)(w + 82529280); // 2,654,208 B
    unsigned short* qt   = (unsigned short*)(w + 85183488); // 2,654,208 B
    unsigned short* kt   = (unsigned short*)(w + 87837696); // 2,367,488 B
    unsigned short* vb   = (unsigned short*)(w + 90205184); // 2,375,680 B
    unsigned short* wqb  = (unsigned short*)(w + 92580864); // 294,912 B
    unsigned short* wkvb = (unsigned short*)(w + 92875776); // 589,824 B
    float* hconst       = (float*)(w + 93465600);           // 512 B
    // hbuf aliases qt/kt/vb (dead after k_av; h-conv runs after k_av)
    float* hbuf         = (float*)(w + 85183488);           // 5,308,416 B

    hipLaunchKernelGGL(k_const, dim3(1), dim3(128), 0, stream, c0, w_vc, w_h, b_h, hconst);
    hipLaunchKernelGGL(k_cast_w, dim3(576), dim3(256), 0, stream, w_qx, w_kx, w_vx, wqb, wkvb);

    // x = proj_x(inp) + b_x   (fp32 + bf16 mirror)
    hipLaunchKernelGGL(k_conv1x1, dim3(21, 2, NN), dim3(256), 0, stream,
                       inp, inp, w_x, b_x, x, x_bf, 128, 128, 128, 0);

    // q (SAME), k+v (VALID) as MFMA implicit GEMM
    hipLaunchKernelGGL(k_conv_q, dim3(21, NN), dim3(256), 0, stream, x_bf, wqb, qt);
    hipLaunchKernelGGL(k_conv_kv, dim3(19, NN), dim3(256), 0, stream, x_bf, wkvb, kt, vb);

    // attention
    hipLaunchKernelGGL(k_scores, dim3(10, 11, NN), dim3(256), 0, stream, qt, kt, sc);
    hipLaunchKernelGGL(k_softmax, dim3(NN * PP), dim3(256), 0, stream, sc, attn);
    hipLaunchKernelGGL(k_av, dim3(21, NN), dim3(256), 0, stream, vb, attn, a0);

    // h = tanh(w_h . [x ; a0] + hconst)
    hipLaunchKernelGGL(k_conv1x1, dim3(21, 2, NN), dim3(256), 0, stream,
                       x, a0, w_h, hconst, hbuf, (unsigned short*)nullptr, 128, 256, 384, 1);

    // out = w_o . h + b_o
    hipLaunchKernelGGL(k_conv1x1, dim3(21, 2, NN), dim3(256), 0, stream,
                       hbuf, hbuf, w_o, b_o, out, (unsigned short*)nullptr, 128, 128, 128, 0);
}

// Round 3
// 263.726 us; speedup vs baseline: 6.7696x; 1.9079x over previous
//
#include <hip/hip_runtime.h>
#include <hip/hip_bf16.h>
#include <math.h>

#define NN 8
#define CH 128
#define HH 36
#define WWI 36
#define PP 1296      // 36*36
#define DD 1156      // 34*34
#define DP 1160      // v row pitch (shorts)
#define KC 1152      // 128*9

typedef __attribute__((ext_vector_type(8))) short short8;
typedef __attribute__((ext_vector_type(4))) float f32x4;

__device__ inline unsigned short f2bf(float f) {
    __hip_bfloat16 h = __float2bfloat16(f);
    return __builtin_bit_cast(unsigned short, h);
}
__device__ inline unsigned int pack2(float a, float b) {
    return (unsigned int)f2bf(a) | ((unsigned int)f2bf(b) << 16);
}

// ---------------------------------------------------------------------------
// hconst[co] = b_h[co] + sum_ci w_h[co,256+ci] * vc[ci];  vc from the folded
// c-branch attention (spatially-uniform c => uniform softmax => constant).
// ---------------------------------------------------------------------------
__global__ void k_const(const float* __restrict__ c0, const float* __restrict__ w_vc,
                        const float* __restrict__ w_h, const float* __restrict__ b_h,
                        float* __restrict__ hconst)
{
    __shared__ float vc[CH];
    int c = threadIdx.x;
    float s = 0.f;
    for (int ci = 0; ci < CH; ++ci) {
        const float* wp = w_vc + ((size_t)c * CH + ci) * 9;
        float ws = 0.f;
#pragma unroll
        for (int k = 0; k < 9; ++k) ws += wp[k];
        s += c0[ci] * ws;
    }
    vc[c] = s;
    __syncthreads();
    float hs = b_h[c];
    for (int ci = 0; ci < CH; ++ci) hs += w_h[(size_t)c * (3 * CH) + 2 * CH + ci] * vc[ci];
    hconst[c] = hs;
}

// ---------------------------------------------------------------------------
// weight cast/reorder:
//  wq_r/wkv_r: [co][tap*128+ci] (tap-major K so conv staging is vectorized)
//  whb: [co][256] = w_h[:, 0:256];  wob: [co][128]
// ---------------------------------------------------------------------------
__global__ void k_cast_w(const float* __restrict__ wq, const float* __restrict__ wk,
                         const float* __restrict__ wv, const float* __restrict__ wh,
                         const float* __restrict__ wo,
                         unsigned short* __restrict__ wq_r, unsigned short* __restrict__ wkv_r,
                         unsigned short* __restrict__ whb, unsigned short* __restrict__ wob)
{
    int t = blockIdx.x * 256 + threadIdx.x;    // 0..147455
    int co = t / KC;
    int rem = t - co * KC;
    int tap = rem >> 7, ci = rem & 127;
    int iidx = co * KC + ci * 9 + tap;
    wq_r[t] = f2bf(wq[iidx]);
    wkv_r[t] = f2bf(wk[iidx]);
    wkv_r[147456 + t] = f2bf(wv[iidx]);
    if (t < 32768) {
        int c2 = t >> 8, k2 = t & 255;
        whb[t] = f2bf(wh[c2 * 384 + k2]);
    }
    if (t < 16384) wob[t] = f2bf(wo[t]);
}

// ---------------------------------------------------------------------------
// proj: fp32 1x1 conv, output transposed bf16 xt[p][c]
// ---------------------------------------------------------------------------
__global__ __launch_bounds__(256)
void k_proj(const float* __restrict__ in0, const float* __restrict__ W,
            const float* __restrict__ bias, unsigned short* __restrict__ xt)
{
    __shared__ float s_in[32][64];
    __shared__ float s_w[32][68];
    const int t = threadIdx.x;
    const int tx = t & 15, ty = t >> 4;
    const int pbase = blockIdx.x * 64;
    const int cobase = blockIdx.y * 64;
    const int n = blockIdx.z;
    float acc[4][4] = {};

    for (int kb = 0; kb < 128; kb += 32) {
#pragma unroll
        for (int r = 0; r < 8; ++r) {
            int lin = t + r * 256;
            int ci = lin >> 6, pl = lin & 63;
            int p = pbase + pl;
            s_in[ci][pl] = (p < PP) ? in0[(size_t)(n * CH + kb + ci) * PP + p] : 0.f;
        }
#pragma unroll
        for (int r = 0; r < 8; ++r) {
            int lin = t + r * 256;
            int col = lin >> 5;
            int cil = lin & 31;
            s_w[cil][col] = W[(size_t)(cobase + col) * CH + kb + cil];
        }
        __syncthreads();
#pragma unroll
        for (int kk = 0; kk < 32; ++kk) {
            float4 i4 = *(const float4*)&s_in[kk][tx * 4];
            float4 w4 = *(const float4*)&s_w[kk][ty * 4];
            float iv[4] = {i4.x, i4.y, i4.z, i4.w};
            float wv[4] = {w4.x, w4.y, w4.z, w4.w};
#pragma unroll
            for (int v = 0; v < 4; ++v)
#pragma unroll
                for (int u = 0; u < 4; ++u) acc[v][u] += wv[v] * iv[u];
        }
        __syncthreads();
    }

    int p0 = pbase + tx * 4;
    int co0 = cobase + ty * 4;
    float bv[4];
#pragma unroll
    for (int v = 0; v < 4; ++v) bv[v] = bias[co0 + v];
#pragma unroll
    for (int u = 0; u < 4; ++u) {
        int p = p0 + u;
        if (p < PP) {
            uint2 o;
            o.x = pack2(acc[0][u] + bv[0], acc[1][u] + bv[1]);
            o.y = pack2(acc[2][u] + bv[2], acc[3][u] + bv[3]);
            *(uint2*)&xt[((size_t)n * PP + p) * CH + co0] = o;
        }
    }
}

// ---------------------------------------------------------------------------
// q conv (3x3 SAME): MFMA implicit GEMM, M=128 co, N=64 p, K=1152 (tap-major).
// out qt[p][co] bf16.
// ---------------------------------------------------------------------------
__global__ __launch_bounds__(256)
void k_conv_q(const unsigned short* __restrict__ xt, const unsigned short* __restrict__ wb,
              unsigned short* __restrict__ qt)
{
    __shared__ unsigned short la[CH * 40];
    __shared__ unsigned short lb[64 * 40];
    const int t = threadIdx.x;
    const int wave = t >> 6, lane = t & 63;
    const int quad = lane >> 4, lrow = lane & 15;
    const int pbase = blockIdx.x * 64;
    const int n = blockIdx.y;
    const unsigned short* xn = xt + (size_t)n * PP * CH;

    const int srow = t >> 2, sseg = (t & 3) * 8;
    const int sp = pbase + srow;
    const int spr = sp / 36, spc = sp - spr * 36;
    const int mbase = wave * 32;
    f32x4 acc[2][4] = {};

    for (int kb = 0; kb < KC; kb += 32) {
        int tap = kb >> 7, ci0 = kb & 127;
        int ky = tap / 3, kx = tap - ky * 3;
#pragma unroll
        for (int r = 0; r < 2; ++r) {
            int row = r * 64 + srow;
            *(uint4*)&la[row * 40 + sseg] = *(const uint4*)&wb[(size_t)row * KC + kb + sseg];
        }
        {
            int yy = spr + ky - 1, xx = spc + kx - 1;
            uint4 val = make_uint4(0, 0, 0, 0);
            if (sp < PP && yy >= 0 && yy < HH && xx >= 0 && xx < WWI)
                val = *(const uint4*)&xn[(size_t)(yy * WWI + xx) * CH + ci0 + sseg];
            *(uint4*)&lb[srow * 40 + sseg] = val;
        }
        __syncthreads();
        short8 afr[2], bfr[4];
#pragma unroll
        for (int mi = 0; mi < 2; ++mi)
            afr[mi] = *(const short8*)&la[(mbase + mi * 16 + lrow) * 40 + quad * 8];
#pragma unroll
        for (int ni = 0; ni < 4; ++ni)
            bfr[ni] = *(const short8*)&lb[(ni * 16 + lrow) * 40 + quad * 8];
#pragma unroll
        for (int mi = 0; mi < 2; ++mi)
#pragma unroll
            for (int ni = 0; ni < 4; ++ni)
                acc[mi][ni] = __builtin_amdgcn_mfma_f32_16x16x32_bf16(afr[mi], bfr[ni], acc[mi][ni], 0, 0, 0);
        __syncthreads();
    }

    unsigned short* qn = qt + (size_t)n * PP * CH;
#pragma unroll
    for (int ni = 0; ni < 4; ++ni) {
        int p = pbase + ni * 16 + lrow;
        if (p < PP) {
#pragma unroll
            for (int mi = 0; mi < 2; ++mi) {
                int co0 = mbase + mi * 16 + quad * 4;
                uint2 u;
                u.x = pack2(acc[mi][ni][0], acc[mi][ni][1]);
                u.y = pack2(acc[mi][ni][2], acc[mi][ni][3]);
                *(uint2*)&qn[(size_t)p * CH + co0] = u;
            }
        }
    }
}

// ---------------------------------------------------------------------------
// k+v conv (3x3 VALID) fused: M=256 (k:0..127, v:128..255), N=64 d, K=1152.
// kt[d][co] bf16 (pack store); v[c][DP] bf16 (scalar store).
// ---------------------------------------------------------------------------
__global__ __launch_bounds__(256)
void k_conv_kv(const unsigned short* __restrict__ xt, const unsigned short* __restrict__ wb,
               unsigned short* __restrict__ kt, unsigned short* __restrict__ vb)
{
    __shared__ unsigned short la[256 * 40];
    __shared__ unsigned short lb[64 * 40];
    const int t = threadIdx.x;
    const int wave = t >> 6, lane = t & 63;
    const int quad = lane >> 4, lrow = lane & 15;
    const int dbase = blockIdx.x * 64;
    const int n = blockIdx.y;
    const unsigned short* xn = xt + (size_t)n * PP * CH;

    const int srow = t >> 2, sseg = (t & 3) * 8;
    const int sd = dbase + srow;
    const int spr = sd / 34, spc = sd - spr * 34;
    const bool sok = sd < DD;
    const int mbase = wave * 64;
    f32x4 acc[4][4] = {};

    for (int kb = 0; kb < KC; kb += 32) {
        int tap = kb >> 7, ci0 = kb & 127;
        int ky = tap / 3, kx = tap - ky * 3;
#pragma unroll
        for (int r = 0; r < 4; ++r) {
            int row = r * 64 + srow;
            *(uint4*)&la[row * 40 + sseg] = *(const uint4*)&wb[(size_t)row * KC + kb + sseg];
        }
        {
            uint4 val = make_uint4(0, 0, 0, 0);
            if (sok)
                val = *(const uint4*)&xn[(size_t)((spr + ky) * WWI + spc + kx) * CH + ci0 + sseg];
            *(uint4*)&lb[srow * 40 + sseg] = val;
        }
        __syncthreads();
        short8 afr[4], bfr[4];
#pragma unroll
        for (int mi = 0; mi < 4; ++mi)
            afr[mi] = *(const short8*)&la[(mbase + mi * 16 + lrow) * 40 + quad * 8];
#pragma unroll
        for (int ni = 0; ni < 4; ++ni)
            bfr[ni] = *(const short8*)&lb[(ni * 16 + lrow) * 40 + quad * 8];
#pragma unroll
        for (int mi = 0; mi < 4; ++mi)
#pragma unroll
            for (int ni = 0; ni < 4; ++ni)
                acc[mi][ni] = __builtin_amdgcn_mfma_f32_16x16x32_bf16(afr[mi], bfr[ni], acc[mi][ni], 0, 0, 0);
        __syncthreads();
    }

    unsigned short* kn = kt + (size_t)n * DD * CH;
    unsigned short* vn = vb + (size_t)n * CH * DP;
#pragma unroll
    for (int ni = 0; ni < 4; ++ni) {
        int d = dbase + ni * 16 + lrow;
        if (d < DD) {
#pragma unroll
            for (int mi = 0; mi < 4; ++mi) {
                int m = mbase + mi * 16 + quad * 4;
                if (m < 128) {
                    uint2 u;
                    u.x = pack2(acc[mi][ni][0], acc[mi][ni][1]);
                    u.y = pack2(acc[mi][ni][2], acc[mi][ni][3]);
                    *(uint2*)&kn[(size_t)d * CH + m] = u;
                } else {
#pragma unroll
                    for (int r = 0; r < 4; ++r)
                        vn[(size_t)(m - 128 + r) * DP + d] = f2bf(acc[mi][ni][r]);
                }
            }
        }
    }
}

// ---------------------------------------------------------------------------
// fused flash attention: per block 64 q rows (wave w: 16 rows), loop 10
// d-tiles of 128: S=Q.K^T (MFMA) -> online softmax -> O += P.V (MFMA).
// out a0t[q][c] bf16.
// ---------------------------------------------------------------------------
__global__ __launch_bounds__(256)
void k_attn(const unsigned short* __restrict__ qt, const unsigned short* __restrict__ kt,
            const unsigned short* __restrict__ vb, unsigned short* __restrict__ a0t)
{
    __shared__ unsigned short lk[128 * 136];      // K tile [d][c]
    __shared__ unsigned short lv[128 * 136];      // V tile [c][d]
    __shared__ unsigned short lp[4][16 * 136];    // per-wave P [q][d]
    const int t = threadIdx.x;
    const int wave = t >> 6, lane = t & 63;
    const int quad = lane >> 4, lrow = lane & 15;
    const int qbase = blockIdx.x * 64;
    const int n = blockIdx.y;
    const unsigned short* qn = qt + (size_t)n * PP * CH;
    const unsigned short* kn = kt + (size_t)n * DD * CH;
    const unsigned short* vn = vb + (size_t)n * CH * DP;
    unsigned short* an = a0t + (size_t)n * PP * CH;

    const int q0 = qbase + wave * 16;
    int qr = q0 + lrow; if (qr >= PP) qr = PP - 1;
    short8 qa[4];
#pragma unroll
    for (int ks = 0; ks < 4; ++ks)
        qa[ks] = *(const short8*)&qn[(size_t)qr * CH + ks * 32 + quad * 8];

    f32x4 o[8] = {};
    float mm[4] = {-1e30f, -1e30f, -1e30f, -1e30f};
    float ll[4] = {0.f, 0.f, 0.f, 0.f};

    for (int dt = 0; dt < 10; ++dt) {
        const int d0 = dt * 128;
        // stage K tile
#pragma unroll
        for (int r = 0; r < 8; ++r) {
            int lin = t + r * 256;
            int row = lin >> 4, seg = (lin & 15) * 8;
            uint4 val = make_uint4(0, 0, 0, 0);
            if (d0 + row < DD) val = *(const uint4*)&kn[(size_t)(d0 + row) * CH + seg];
            *(uint4*)&lk[row * 136 + seg] = val;
        }
        // stage V tile
        if (d0 + 128 <= DD) {
#pragma unroll
            for (int r = 0; r < 8; ++r) {
                int lin = t + r * 256;
                int row = lin >> 4, seg = (lin & 15) * 8;
                *(uint4*)&lv[row * 136 + seg] = *(const uint4*)&vn[(size_t)row * DP + d0 + seg];
            }
        } else {
#pragma unroll
            for (int r = 0; r < 8; ++r) {
                int lin = t + r * 256;
                int row = lin >> 4, seg = (lin & 15) * 8;
#pragma unroll
                for (int j = 0; j < 8; ++j) {
                    int dg = d0 + seg + j;
                    lv[row * 136 + seg + j] = (dg < DD) ? vn[(size_t)row * DP + dg] : 0;
                }
            }
        }
        __syncthreads();

        // S = Q.K^T
        f32x4 s[8] = {};
#pragma unroll
        for (int ks = 0; ks < 4; ++ks)
#pragma unroll
            for (int ni = 0; ni < 8; ++ni) {
                short8 b = *(const short8*)&lk[(ni * 16 + lrow) * 136 + ks * 32 + quad * 8];
                s[ni] = __builtin_amdgcn_mfma_f32_16x16x32_bf16(qa[ks], b, s[ni], 0, 0, 0);
            }

        // mask + row max
        float mx[4] = {-1e30f, -1e30f, -1e30f, -1e30f};
#pragma unroll
        for (int ni = 0; ni < 8; ++ni) {
            int dcol = d0 + ni * 16 + lrow;
            if (dcol >= DD) {
#pragma unroll
                for (int r = 0; r < 4; ++r) s[ni][r] = -1e30f;
            }
#pragma unroll
            for (int r = 0; r < 4; ++r) mx[r] = fmaxf(mx[r], s[ni][r]);
        }
#pragma unroll
        for (int off = 1; off < 16; off <<= 1)
#pragma unroll
            for (int r = 0; r < 4; ++r) mx[r] = fmaxf(mx[r], __shfl_xor(mx[r], off, 64));

        float al[4], rs[4] = {0.f, 0.f, 0.f, 0.f};
#pragma unroll
        for (int r = 0; r < 4; ++r) {
            float mn = fmaxf(mm[r], mx[r]);
            al[r] = __expf(mm[r] - mn);
            mm[r] = mn;
        }
        // P = exp(S - m), row sums, write P to wave LDS
#pragma unroll
        for (int ni = 0; ni < 8; ++ni)
#pragma unroll
            for (int r = 0; r < 4; ++r) {
                float e = __expf(s[ni][r] - mm[r]);
                s[ni][r] = e;
                rs[r] += e;
            }
#pragma unroll
        for (int off = 1; off < 16; off <<= 1)
#pragma unroll
            for (int r = 0; r < 4; ++r) rs[r] += __shfl_xor(rs[r], off, 64);
#pragma unroll
        for (int r = 0; r < 4; ++r) ll[r] = ll[r] * al[r] + rs[r];
#pragma unroll
        for (int ni = 0; ni < 8; ++ni)
#pragma unroll
            for (int r = 0; r < 4; ++r) o[ni][r] *= al[r];
#pragma unroll
        for (int ni = 0; ni < 8; ++ni)
#pragma unroll
            for (int r = 0; r < 4; ++r)
                lp[wave][(quad * 4 + r) * 136 + ni * 16 + lrow] = f2bf(s[ni][r]);

        // O += P.V   (wave-private LDS round trip for P)
        short8 pa[4];
#pragma unroll
        for (int ks = 0; ks < 4; ++ks)
            pa[ks] = *(const short8*)&lp[wave][lrow * 136 + ks * 32 + quad * 8];
#pragma unroll
        for (int ks = 0; ks < 4; ++ks)
#pragma unroll
            for (int ni = 0; ni < 8; ++ni) {
                short8 b = *(const short8*)&lv[(ni * 16 + lrow) * 136 + ks * 32 + quad * 8];
                o[ni] = __builtin_amdgcn_mfma_f32_16x16x32_bf16(pa[ks], b, o[ni], 0, 0, 0);
            }
        __syncthreads();
    }

    float inv[4];
#pragma unroll
    for (int r = 0; r < 4; ++r) inv[r] = 1.f / ll[r];
#pragma unroll
    for (int ni = 0; ni < 8; ++ni)
#pragma unroll
        for (int r = 0; r < 4; ++r) {
            int qg = q0 + quad * 4 + r;
            if (qg < PP) an[(size_t)qg * CH + ni * 16 + lrow] = f2bf(o[ni][r] * inv[r]);
        }
}

// ---------------------------------------------------------------------------
// h = tanh(whb . [xt;a0t] + hconst): M=128 co, N=64 p, K=256. out ht[p][co].
// ---------------------------------------------------------------------------
__global__ __launch_bounds__(256)
void k_h(const unsigned short* __restrict__ xt, const unsigned short* __restrict__ a0t,
         const unsigned short* __restrict__ whb, const float* __restrict__ hconst,
         unsigned short* __restrict__ ht)
{
    __shared__ unsigned short la[CH * 40];
    __shared__ unsigned short lb[64 * 40];
    const int t = threadIdx.x;
    const int wave = t >> 6, lane = t & 63;
    const int quad = lane >> 4, lrow = lane & 15;
    const int pbase = blockIdx.x * 64;
    const int n = blockIdx.y;
    const unsigned short* x0 = xt + (size_t)n * PP * CH;
    const unsigned short* a0 = a0t + (size_t)n * PP * CH;
    const int srow = t >> 2, sseg = (t & 3) * 8;
    int sp = pbase + srow; if (sp >= PP) sp = PP - 1;
    const int mbase = wave * 32;
    f32x4 acc[2][4] = {};

    for (int kb = 0; kb < 256; kb += 32) {
#pragma unroll
        for (int r = 0; r < 2; ++r) {
            int row = r * 64 + srow;
            *(uint4*)&la[row * 40 + sseg] = *(const uint4*)&whb[(size_t)row * 256 + kb + sseg];
        }
        {
            const unsigned short* src = (kb < 128) ? &x0[(size_t)sp * CH + kb + sseg]
                                                   : &a0[(size_t)sp * CH + kb - 128 + sseg];
            *(uint4*)&lb[srow * 40 + sseg] = *(const uint4*)src;
        }
        __syncthreads();
        short8 afr[2], bfr[4];
#pragma unroll
        for (int mi = 0; mi < 2; ++mi)
            afr[mi] = *(const short8*)&la[(mbase + mi * 16 + lrow) * 40 + quad * 8];
#pragma unroll
        for (int ni = 0; ni < 4; ++ni)
            bfr[ni] = *(const short8*)&lb[(ni * 16 + lrow) * 40 + quad * 8];
#pragma unroll
        for (int mi = 0; mi < 2; ++mi)
#pragma unroll
            for (int ni = 0; ni < 4; ++ni)
                acc[mi][ni] = __builtin_amdgcn_mfma_f32_16x16x32_bf16(afr[mi], bfr[ni], acc[mi][ni], 0, 0, 0);
        __syncthreads();
    }

    unsigned short* hn = ht + (size_t)n * PP * CH;
#pragma unroll
    for (int ni = 0; ni < 4; ++ni) {
        int p = pbase + ni * 16 + lrow;
        if (p < PP) {
#pragma unroll
            for (int mi = 0; mi < 2; ++mi) {
                int co0 = mbase + mi * 16 + quad * 4;
                float v0 = tanhf(acc[mi][ni][0] + hconst[co0]);
                float v1 = tanhf(acc[mi][ni][1] + hconst[co0 + 1]);
                float v2 = tanhf(acc[mi][ni][2] + hconst[co0 + 2]);
                float v3 = tanhf(acc[mi][ni][3] + hconst[co0 + 3]);
                uint2 u;
                u.x = pack2(v0, v1); u.y = pack2(v2, v3);
                *(uint2*)&hn[(size_t)p * CH + co0] = u;
            }
        }
    }
}

// ---------------------------------------------------------------------------
// out[n][co][p] = wob . ht + b_o : M=128 co, N=64 p, K=128, fp32 out.
// ---------------------------------------------------------------------------
__global__ __launch_bounds__(256)
void k_out(const unsigned short* __restrict__ ht, const unsigned short* __restrict__ wob,
           const float* __restrict__ bo, float* __restrict__ out)
{
    __shared__ unsigned short la[CH * 40];
    __shared__ unsigned short lb[64 * 40];
    const int t = threadIdx.x;
    const int wave = t >> 6, lane = t & 63;
    const int quad = lane >> 4, lrow = lane & 15;
    const int pbase = blockIdx.x * 64;
    const int n = blockIdx.y;
    const unsigned short* hn = ht + (size_t)n * PP * CH;
    const int srow = t >> 2, sseg = (t & 3) * 8;
    int sp = pbase + srow; if (sp >= PP) sp = PP - 1;
    const int mbase = wave * 32;
    f32x4 acc[2][4] = {};

    for (int kb = 0; kb < 128; kb += 32) {
#pragma unroll
        for (int r = 0; r < 2; ++r) {
            int row = r * 64 + srow;
            *(uint4*)&la[row * 40 + sseg] = *(const uint4*)&wob[(size_t)row * CH + kb + sseg];
        }
        *(uint4*)&lb[srow * 40 + sseg] = *(const uint4*)&hn[(size_t)sp * CH + kb + sseg];
        __syncthreads();
        short8 afr[2], bfr[4];
#pragma unroll
        for (int mi = 0; mi < 2; ++mi)
            afr[mi] = *(const short8*)&la[(mbase + mi * 16 + lrow) * 40 + quad * 8];
#pragma unroll
        for (int ni = 0; ni < 4; ++ni)
            bfr[ni] = *(const short8*)&lb[(ni * 16 + lrow) * 40 + quad * 8];
#pragma unroll
        for (int mi = 0; mi < 2; ++mi)
#pragma unroll
            for (int ni = 0; ni < 4; ++ni)
                acc[mi][ni] = __builtin_amdgcn_mfma_f32_16x16x32_bf16(afr[mi], bfr[ni], acc[mi][ni], 0, 0, 0);
        __syncthreads();
    }

#pragma unroll
    for (int ni = 0; ni < 4; ++ni) {
        int p = pbase + ni * 16 + lrow;
        if (p < PP) {
#pragma unroll
            for (int mi = 0; mi < 2; ++mi)
#pragma unroll
                for (int r = 0; r < 4; ++r) {
                    int co = mbase + mi * 16 + quad * 4 + r;
                    out[((size_t)(n * CH + co)) * PP + p] = acc[mi][ni][r] + bo[co];
                }
        }
    }
}

// ---------------------------------------------------------------------------
extern "C" void kernel_launch(void* const* d_in, const int* in_sizes, int n_in,
                              void* d_out, int out_size, void* d_ws, size_t ws_size,
                              hipStream_t stream)
{
    const float* inp  = (const float*)d_in[0];
    const float* c0   = (const float*)d_in[1];
    const float* w_x  = (const float*)d_in[2];
    const float* b_x  = (const float*)d_in[3];
    const float* w_qx = (const float*)d_in[4];
    const float* w_kx = (const float*)d_in[6];
    const float* w_vx = (const float*)d_in[8];
    const float* w_vc = (const float*)d_in[9];
    const float* w_h  = (const float*)d_in[14];
    const float* b_h  = (const float*)d_in[15];
    const float* w_o  = (const float*)d_in[16];
    const float* b_o  = (const float*)d_in[17];
    float* out = (float*)d_out;

    char* w = (char*)d_ws;
    unsigned short* xt   = (unsigned short*)(w);             // 2,654,208 B
    unsigned short* qt   = (unsigned short*)(w + 2654208);   // 2,654,208 B
    unsigned short* kt   = (unsigned short*)(w + 5308416);   // 2,367,488 B
    unsigned short* vb   = (unsigned short*)(w + 7675904);   // 2,375,680 B
    unsigned short* a0t  = (unsigned short*)(w + 10051584);  // 2,654,208 B
    unsigned short* ht   = (unsigned short*)(w + 12705792);  // 2,654,208 B
    unsigned short* wqr  = (unsigned short*)(w + 15360000);  // 294,912 B
    unsigned short* wkvr = (unsigned short*)(w + 15654912);  // 589,824 B
    unsigned short* whb  = (unsigned short*)(w + 16244736);  // 65,536 B
    unsigned short* wob  = (unsigned short*)(w + 16310272);  // 32,768 B
    float* hconst        = (float*)(w + 16343040);           // 512 B

    hipLaunchKernelGGL(k_const, dim3(1), dim3(128), 0, stream, c0, w_vc, w_h, b_h, hconst);
    hipLaunchKernelGGL(k_cast_w, dim3(576), dim3(256), 0, stream,
                       w_qx, w_kx, w_vx, w_h, w_o, wqr, wkvr, whb, wob);

    hipLaunchKernelGGL(k_proj, dim3(21, 2, NN), dim3(256), 0, stream, inp, w_x, b_x, xt);

    hipLaunchKernelGGL(k_conv_q, dim3(21, NN), dim3(256), 0, stream, xt, wqr, qt);
    hipLaunchKernelGGL(k_conv_kv, dim3(19, NN), dim3(256), 0, stream, xt, wkvr, kt, vb);

    hipLaunchKernelGGL(k_attn, dim3(21, NN), dim3(256), 0, stream, qt, kt, vb, a0t);

    hipLaunchKernelGGL(k_h, dim3(21, NN), dim3(256), 0, stream, xt, a0t, whb, hconst, ht);
    hipLaunchKernelGGL(k_out, dim3(21, NN), dim3(256), 0, stream, ht, wob, b_o, out);
}